// Round 23
// baseline (929.330 us; speedup 1.0000x reference)
//
#include <hip/hip_runtime.h>

// QSScan: quantized selective scan (Mamba-style), int8-in-int32 + scalar scales.
// Chunked parallel linear recurrence, serial-in-thread, DIRECT register staging.
//   phase1: thread=(scan,chunk): local scan from 0 over LC=32 -> X_end[16], S=sum(delta)
//   combine: thread=(scan,n): fold 64 chunks -> true init per chunk
//   phase2: thread=(scan,chunk): rerun from true init -> y=(x.C)*C_s+D*u, silu(z) gate
// R23 vs R22 (BCf-from-global regressed 149->190: per-step global uniform reads
// lose to LDS broadcast -> reverted) and vs R21 (90us/phase, occupancy 36-46%,
// LDS pipe triple-loaded by staging writes + byte reads + B/C broadcasts):
//   - u/dt/z LDS staging DELETED: each thread's chunk is its own contiguous
//     128B line -> 8 back-to-back int4 loads per stream, packed to 8 VGPR words.
//     One-shot line consumption (not R5's scattered revisits) -> FETCH stays
//     ideal; kills 24 ds_writes + per-step ds_read_u8 + 25.6KB LDS.
//   - only B/C float tiles remain in LDS (5.2KB p2 / 2.6KB p1) -> occupancy
//     VGPR-capped ~23-28 waves/CU instead of LDS-capped ~11.
//   - keep ya[16] 64B sector-burst stores (R19) + full-line loads (R21)

#define LOG2E 1.44269504088896340736f
#define LN2F  0.69314718055994530942f

constexpr int BATCH = 2;
constexpr int DIM   = 4096;
constexpr int LSEQ  = 2048;
constexpr int NST   = 16;
constexpr int SCANS = BATCH * DIM;   // 8192
constexpr int K     = 64;            // chunks per scan
constexpr int LC    = LSEQ / K;      // 32 timesteps per chunk (= one 128B line)
constexpr int SPB   = 256;           // scans per block (1 chunk per block)
constexpr int NSG   = SCANS / SPB;   // 32 scan-groups

__device__ __forceinline__ float softplus_f(float x) {
    float e = __builtin_amdgcn_exp2f(x * LOG2E);
    return __builtin_amdgcn_logf(1.f + e) * LN2F;
}

__device__ __forceinline__ int pack8(int4 v) {   // values in [-127,127]: exact
    return (v.x & 255) | ((v.y & 255) << 8) | ((v.z & 255) << 16) | ((v.w & 255) << 24);
}

__device__ __forceinline__ float sb(int w, int b) {   // signed byte b of word w
    return (float)((signed char)(w >> (8 * b)));
}

#define LOAD_A2()                                                              \
    float A2[NST];                                                             \
    {                                                                          \
        const int4* ap = (const int4*)(A_log + d * NST);                       \
        int4 a0 = ap[0], a1 = ap[1], a2 = ap[2], a3 = ap[3];                   \
        const int ai[NST] = {a0.x,a0.y,a0.z,a0.w, a1.x,a1.y,a1.z,a1.w,         \
                             a2.x,a2.y,a2.z,a2.w, a3.x,a3.y,a3.z,a3.w};        \
        _Pragma("unroll")                                                      \
        for (int n = 0; n < NST; ++n)                                          \
            A2[n] = -__builtin_amdgcn_exp2f((float)ai[n] * (A_s * LOG2E)) * LOG2E; \
    }

// advance 4 states (q-th quad) and accumulate y; keeps only 2 float4 live
#define STEP4(q, bt, ct)                                                       \
    {                                                                          \
        const float4 Bq = *(const float4*)((bt) + 4 * (q));                    \
        const float4 Cq = *(const float4*)((ct) + 4 * (q));                    \
        x[4*(q)+0] = __builtin_fmaf(__builtin_amdgcn_exp2f(A2[4*(q)+0] * delta), x[4*(q)+0], w * Bq.x); \
        y = __builtin_fmaf(x[4*(q)+0], Cq.x, y);                               \
        x[4*(q)+1] = __builtin_fmaf(__builtin_amdgcn_exp2f(A2[4*(q)+1] * delta), x[4*(q)+1], w * Bq.y); \
        y = __builtin_fmaf(x[4*(q)+1], Cq.y, y);                               \
        x[4*(q)+2] = __builtin_fmaf(__builtin_amdgcn_exp2f(A2[4*(q)+2] * delta), x[4*(q)+2], w * Bq.z); \
        y = __builtin_fmaf(x[4*(q)+2], Cq.z, y);                               \
        x[4*(q)+3] = __builtin_fmaf(__builtin_amdgcn_exp2f(A2[4*(q)+3] * delta), x[4*(q)+3], w * Bq.w); \
        y = __builtin_fmaf(x[4*(q)+3], Cq.w, y);                               \
    }

#define STEP4B(q, bt)                                                          \
    {                                                                          \
        const float4 Bq = *(const float4*)((bt) + 4 * (q));                    \
        x[4*(q)+0] = __builtin_fmaf(__builtin_amdgcn_exp2f(A2[4*(q)+0] * delta), x[4*(q)+0], w * Bq.x); \
        x[4*(q)+1] = __builtin_fmaf(__builtin_amdgcn_exp2f(A2[4*(q)+1] * delta), x[4*(q)+1], w * Bq.y); \
        x[4*(q)+2] = __builtin_fmaf(__builtin_amdgcn_exp2f(A2[4*(q)+2] * delta), x[4*(q)+2], w * Bq.z); \
        x[4*(q)+3] = __builtin_fmaf(__builtin_amdgcn_exp2f(A2[4*(q)+3] * delta), x[4*(q)+3], w * Bq.w); \
    }

// ---------------- Phase 1: per-chunk summaries (X_end, S) ----------------
__global__ __launch_bounds__(256, 4) void qs_phase1(
    const int* __restrict__ u,  const int* __restrict__ dt,
    const int* __restrict__ Bm, const int* __restrict__ A_log,
    const int* __restrict__ dt_bias,
    const float* __restrict__ u_sp, const float* __restrict__ dt_sp,
    const float* __restrict__ A_sp, const float* __restrict__ B_sp,
    const float* __restrict__ dtb_sp,
    float* __restrict__ Sbuf, float* __restrict__ Xbuf)
{
    const int tid = threadIdx.x;
    const int cg  = blockIdx.x >> 5;           // chunk 0..63
    const int sg  = blockIdx.x & 31;           // scan-group 0..31
    const int scan = sg * SPB + tid;
    const int d  = scan & (DIM - 1);
    const int bb = sg >> 4;                    // batch, uniform per block

    __shared__ float tB[LC * 20];              // 2.6KB: only B tile in LDS

    const float u_s = *u_sp, dt_s = *dt_sp, A_s = *A_sp, B_s = *B_sp, dtb_s = *dtb_sp;

    // direct register staging: own 128B line per stream, 8 back-to-back int4s
    const int* up = u  + scan * LSEQ + cg * LC;
    const int* dp = dt + scan * LSEQ + cg * LC;
    int uw[8], dw[8];
#pragma unroll
    for (int j = 0; j < 8; ++j) uw[j] = pack8(*(const int4*)(up + 4 * j));
#pragma unroll
    for (int j = 0; j < 8; ++j) dw[j] = pack8(*(const int4*)(dp + 4 * j));

    // B tile stage: 32 steps x 16 states (pad 20)
    {
        const int kB = tid & 31, nB0 = tid >> 5;
#pragma unroll
        for (int j2 = 0; j2 < 2; ++j2) {
            const int n = nB0 + 8 * j2;
            tB[kB * 20 + n] = (float)Bm[(bb * NST + n) * LSEQ + cg * LC + kB];
        }
    }

    LOAD_A2();
    const float dtb = (float)dt_bias[d] * dtb_s;
    __syncthreads();

    float x[NST];
#pragma unroll
    for (int n = 0; n < NST; ++n) x[n] = 0.f;
    float S = 0.f;

#pragma unroll
    for (int k4 = 0; k4 < 8; ++k4) {
#pragma unroll
        for (int b = 0; b < 4; ++b) {
            const int k = 4 * k4 + b;
            const float uf    = sb(uw[k4], b) * u_s;
            const float delta = softplus_f(sb(dw[k4], b) * dt_s + dtb);
            const float w     = delta * uf * B_s;
            S += delta;
            const float* bt = &tB[k * 20];
            STEP4B(0, bt); STEP4B(1, bt); STEP4B(2, bt); STEP4B(3, bt);
        }
    }

    Sbuf[cg * SCANS + scan] = S;
    float4* Xo = (float4*)(Xbuf + (cg * SCANS + scan) * NST);
#pragma unroll
    for (int q = 0; q < 4; ++q)
        Xo[q] = make_float4(x[4*q], x[4*q+1], x[4*q+2], x[4*q+3]);
}

// ---------------- Combine: fold summaries, write init states in-place ----------------
__global__ __launch_bounds__(256) void qs_combine(
    const int* __restrict__ A_log, const float* __restrict__ A_sp,
    const float* __restrict__ Sbuf, float* __restrict__ Xbuf)
{
    const int idx  = blockIdx.x * 256 + threadIdx.x;   // flat (scan, n)
    const int scan = idx >> 4, n = idx & 15;
    const int d    = scan & (DIM - 1);
    const float A2 = -__builtin_amdgcn_exp2f(
        (float)A_log[d * NST + n] * ((*A_sp) * LOG2E)) * LOG2E;
    float x = 0.f;
#pragma unroll 8
    for (int c = 0; c < K; ++c) {
        const int off = c * (SCANS * NST) + idx;
        const float Xe = Xbuf[off];
        const float P  = __builtin_amdgcn_exp2f(A2 * Sbuf[c * SCANS + scan]);
        Xbuf[off] = x;                                  // init state for chunk c
        x = __builtin_fmaf(P, x, Xe);
    }
}

// ---------------- Phase 2: rerun with true init, emit output ----------------
__global__ __launch_bounds__(256, 4) void qs_phase2(
    const int* __restrict__ u,  const int* __restrict__ dt,
    const int* __restrict__ Bm, const int* __restrict__ Cm,
    const int* __restrict__ z,  const int* __restrict__ A_log,
    const int* __restrict__ Dv, const int* __restrict__ dt_bias,
    const float* __restrict__ u_sp,  const float* __restrict__ dt_sp,
    const float* __restrict__ A_sp,  const float* __restrict__ B_sp,
    const float* __restrict__ C_sp,  const float* __restrict__ z_sp,
    const float* __restrict__ D_sp,  const float* __restrict__ dtb_sp,
    const float* __restrict__ XI, float* __restrict__ out)
{
    const int tid = threadIdx.x;
    const int cg  = blockIdx.x >> 5;
    const int sg  = blockIdx.x & 31;
    const int scan = sg * SPB + tid;
    const int d  = scan & (DIM - 1);
    const int bb = sg >> 4;

    __shared__ float tB[LC * 20];              // 5.2KB total: only B/C tiles
    __shared__ float tC[LC * 20];

    const float u_s = *u_sp, dt_s = *dt_sp, A_s = *A_sp, B_s = *B_sp;
    const float C_s = *C_sp, z_s  = *z_sp,  D_s = *D_sp, dtb_s = *dtb_sp;

    // direct register staging: own 128B line per stream
    const int* up = u  + scan * LSEQ + cg * LC;
    const int* dp = dt + scan * LSEQ + cg * LC;
    const int* zp = z  + scan * LSEQ + cg * LC;
    int uw[8], dw[8], zw[8];
#pragma unroll
    for (int j = 0; j < 8; ++j) uw[j] = pack8(*(const int4*)(up + 4 * j));
#pragma unroll
    for (int j = 0; j < 8; ++j) dw[j] = pack8(*(const int4*)(dp + 4 * j));
#pragma unroll
    for (int j = 0; j < 8; ++j) zw[j] = pack8(*(const int4*)(zp + 4 * j));

    // B/C tile stage
    {
        const int kB = tid & 31, nB0 = tid >> 5;
#pragma unroll
        for (int j2 = 0; j2 < 2; ++j2) {
            const int n  = nB0 + 8 * j2;
            const int gr = (bb * NST + n) * LSEQ + cg * LC + kB;
            tB[kB * 20 + n] = (float)Bm[gr];
            tC[kB * 20 + n] = (float)Cm[gr];
        }
    }

    LOAD_A2();
    const float dtb = (float)dt_bias[d] * dtb_s;
    const float Dd  = (float)Dv[d] * D_s;

    float x[NST];
    {
        const float4* xi = (const float4*)(XI + (cg * SCANS + scan) * NST);
        const float4 x0 = xi[0], x1 = xi[1], x2 = xi[2], x3 = xi[3];
        x[0]=x0.x; x[1]=x0.y; x[2]=x0.z; x[3]=x0.w;
        x[4]=x1.x; x[5]=x1.y; x[6]=x1.z; x[7]=x1.w;
        x[8]=x2.x; x[9]=x2.y; x[10]=x2.z; x[11]=x2.w;
        x[12]=x3.x; x[13]=x3.y; x[14]=x3.z; x[15]=x3.w;
    }
    __syncthreads();

    const int ob = scan * LSEQ + cg * LC;      // own output row-chunk base
    float ya[16];                              // 64B sector buffer, burst every 16 k
#pragma unroll
    for (int k4 = 0; k4 < 8; ++k4) {
#pragma unroll
        for (int b = 0; b < 4; ++b) {
            const int k = 4 * k4 + b;
            const float uf    = sb(uw[k4], b) * u_s;
            const float delta = softplus_f(sb(dw[k4], b) * dt_s + dtb);
            const float w     = delta * uf * B_s;
            const float zf    = sb(zw[k4], b) * z_s;
            const float gate  = zf * __builtin_amdgcn_rcpf(
                                    1.f + __builtin_amdgcn_exp2f(-zf * LOG2E));
            const float* bt = &tB[k * 20];
            const float* ct = &tC[k * 20];
            float y = 0.f;
            STEP4(0, bt, ct); STEP4(1, bt, ct); STEP4(2, bt, ct); STEP4(3, bt, ct);
            ya[k & 15] = __builtin_fmaf(y, C_s, Dd * uf) * gate;
            if ((k & 15) == 15) {              // 4 back-to-back float4 stores:
                float* ob2 = out + ob + (k - 15);   // one fully-dirty 64B sector
#pragma unroll
                for (int q = 0; q < 4; ++q)
                    *(float4*)(ob2 + 4 * q) =
                        make_float4(ya[4*q], ya[4*q+1], ya[4*q+2], ya[4*q+3]);
            }
        }
    }
}

extern "C" void kernel_launch(void* const* d_in, const int* in_sizes, int n_in,
                              void* d_out, int out_size, void* d_ws, size_t ws_size,
                              hipStream_t stream) {
    const int* u   = (const int*)d_in[0];
    const int* dt  = (const int*)d_in[1];
    const int* Bm  = (const int*)d_in[2];
    const int* Cm  = (const int*)d_in[3];
    const int* z   = (const int*)d_in[4];
    const int* Al  = (const int*)d_in[5];
    const int* Dv  = (const int*)d_in[6];
    const int* dtb = (const int*)d_in[7];
    const float* u_sp = (const float*)d_in[8],  * dt_sp = (const float*)d_in[9];
    const float* A_sp = (const float*)d_in[10], * B_sp  = (const float*)d_in[11];
    const float* C_sp = (const float*)d_in[12], * z_sp  = (const float*)d_in[13];
    const float* D_sp = (const float*)d_in[14], * dtb_sp= (const float*)d_in[15];

    float* Xbuf = (float*)d_ws;                          // K*SCANS*NST f32 = 33.6 MiB
    float* Sbuf = Xbuf + (size_t)K * SCANS * NST;        // K*SCANS f32 = 2.1 MiB

    dim3 blk(256);
    qs_phase1<<<dim3(K * NSG), blk, 0, stream>>>(u, dt, Bm, Al, dtb,
        u_sp, dt_sp, A_sp, B_sp, dtb_sp, Sbuf, Xbuf);
    qs_combine<<<dim3(SCANS * NST / 256), blk, 0, stream>>>(Al, A_sp, Sbuf, Xbuf);
    qs_phase2<<<dim3(K * NSG), blk, 0, stream>>>(u, dt, Bm, Cm, z, Al, Dv, dtb,
        u_sp, dt_sp, A_sp, B_sp, C_sp, z_sp, D_sp, dtb_sp, Xbuf, (float*)d_out);
}

// Round 24
// 782.084 us; speedup vs baseline: 1.1883x; 1.1883x over previous
//
#include <hip/hip_runtime.h>

// QSScan: quantized selective scan (Mamba-style), int8-in-int32 + scalar scales.
// Chunked parallel linear recurrence, serial-in-thread, LDS-transpose-staged I/O.
//   phase1: thread=(scan,chunk): local scan from 0 over LC=32 -> X_end[16], S=sum(delta)
//   combine: thread=(scan,n): fold 64 chunks -> true init per chunk
//   phase2: thread=(scan,chunk): rerun from true init -> y=(x.C)*C_s+D*u, silu(z) gate
// R24 = R21 (best: 149us, traffic ideal, no spill) + R22's one sound piece:
//   - staged u/dt/z read as WORDS (ds_read_b32 per 4 steps per stream) + v_bfe
//     byte extracts, replacing 3 ds_read_u8 per step (~9 fewer LDS insts / 4 steps)
//   - tB/tC LDS broadcast KEPT (R22 proved per-step global uniform reads regress)
//   - R23's register staging REVERTED (spilled: FETCH 1.0GB/WRITE 1.6GB, 6x slower)
//   - keep ya[16] 64B sector-burst stores (R19) + full-line staging loads (R21)

#define LOG2E 1.44269504088896340736f
#define LN2F  0.69314718055994530942f

constexpr int BATCH = 2;
constexpr int DIM   = 4096;
constexpr int LSEQ  = 2048;
constexpr int NST   = 16;
constexpr int SCANS = BATCH * DIM;   // 8192
constexpr int K     = 64;            // chunks per scan
constexpr int LC    = LSEQ / K;      // 32 timesteps per chunk (= one 128B line)
constexpr int SPB   = 256;           // scans per block (1 chunk per block)
constexpr int NSG   = SCANS / SPB;   // 32 scan-groups

__device__ __forceinline__ float softplus_f(float x) {
    float e = __builtin_amdgcn_exp2f(x * LOG2E);
    return __builtin_amdgcn_logf(1.f + e) * LN2F;
}

__device__ __forceinline__ int pack8(int4 v) {   // values in [-127,127]: exact
    return (v.x & 255) | ((v.y & 255) << 8) | ((v.z & 255) << 16) | ((v.w & 255) << 24);
}

__device__ __forceinline__ float sb(int w, int b) {   // signed byte b of word w
    return (float)((signed char)(w >> (8 * b)));
}

#define LOAD_A2()                                                              \
    float A2[NST];                                                             \
    {                                                                          \
        const int4* ap = (const int4*)(A_log + d * NST);                       \
        int4 a0 = ap[0], a1 = ap[1], a2 = ap[2], a3 = ap[3];                   \
        const int ai[NST] = {a0.x,a0.y,a0.z,a0.w, a1.x,a1.y,a1.z,a1.w,         \
                             a2.x,a2.y,a2.z,a2.w, a3.x,a3.y,a3.z,a3.w};        \
        _Pragma("unroll")                                                      \
        for (int n = 0; n < NST; ++n)                                          \
            A2[n] = -__builtin_amdgcn_exp2f((float)ai[n] * (A_s * LOG2E)) * LOG2E; \
    }

// advance 4 states (q-th quad) and accumulate y; keeps only 2 float4 live
#define STEP4(q, bt, ct)                                                       \
    {                                                                          \
        const float4 Bq = *(const float4*)((bt) + 4 * (q));                    \
        const float4 Cq = *(const float4*)((ct) + 4 * (q));                    \
        x[4*(q)+0] = __builtin_fmaf(__builtin_amdgcn_exp2f(A2[4*(q)+0] * delta), x[4*(q)+0], w * Bq.x); \
        y = __builtin_fmaf(x[4*(q)+0], Cq.x, y);                               \
        x[4*(q)+1] = __builtin_fmaf(__builtin_amdgcn_exp2f(A2[4*(q)+1] * delta), x[4*(q)+1], w * Bq.y); \
        y = __builtin_fmaf(x[4*(q)+1], Cq.y, y);                               \
        x[4*(q)+2] = __builtin_fmaf(__builtin_amdgcn_exp2f(A2[4*(q)+2] * delta), x[4*(q)+2], w * Bq.z); \
        y = __builtin_fmaf(x[4*(q)+2], Cq.z, y);                               \
        x[4*(q)+3] = __builtin_fmaf(__builtin_amdgcn_exp2f(A2[4*(q)+3] * delta), x[4*(q)+3], w * Bq.w); \
        y = __builtin_fmaf(x[4*(q)+3], Cq.w, y);                               \
    }

#define STEP4B(q, bt)                                                          \
    {                                                                          \
        const float4 Bq = *(const float4*)((bt) + 4 * (q));                    \
        x[4*(q)+0] = __builtin_fmaf(__builtin_amdgcn_exp2f(A2[4*(q)+0] * delta), x[4*(q)+0], w * Bq.x); \
        x[4*(q)+1] = __builtin_fmaf(__builtin_amdgcn_exp2f(A2[4*(q)+1] * delta), x[4*(q)+1], w * Bq.y); \
        x[4*(q)+2] = __builtin_fmaf(__builtin_amdgcn_exp2f(A2[4*(q)+2] * delta), x[4*(q)+2], w * Bq.z); \
        x[4*(q)+3] = __builtin_fmaf(__builtin_amdgcn_exp2f(A2[4*(q)+3] * delta), x[4*(q)+3], w * Bq.w); \
    }

// ---------------- Phase 1: per-chunk summaries (X_end, S) ----------------
__global__ __launch_bounds__(256, 4) void qs_phase1(
    const int* __restrict__ u,  const int* __restrict__ dt,
    const int* __restrict__ Bm, const int* __restrict__ A_log,
    const int* __restrict__ dt_bias,
    const float* __restrict__ u_sp, const float* __restrict__ dt_sp,
    const float* __restrict__ A_sp, const float* __restrict__ B_sp,
    const float* __restrict__ dtb_sp,
    float* __restrict__ Sbuf, float* __restrict__ Xbuf)
{
    const int tid = threadIdx.x;
    const int cg  = blockIdx.x >> 5;           // chunk 0..63
    const int sg  = blockIdx.x & 31;           // scan-group 0..31
    const int scan = sg * SPB + tid;
    const int d  = scan & (DIM - 1);
    const int bb = sg >> 4;                    // batch, uniform per block

    // per col: u 8w | dt 8w | pad 1w  (stride 17 words, gcd(17,32)=1)
    __shared__ int   sud[256 * 17];
    __shared__ float tB[LC * 20];

    const float u_s = *u_sp, dt_s = *dt_sp, A_s = *A_sp, B_s = *B_sp, dtb_s = *dtb_sp;
    LOAD_A2();
    const float dtb = (float)dt_bias[d] * dtb_s;

    const int lc8 = tid >> 3, lo8 = tid & 7;   // 8 lanes cover one col's 128B line
    const int in0 = sg * SPB * LSEQ + cg * LC;
    const int kB  = tid & 31, nB0 = tid >> 5;  // B-stage role (32k x 8n x 2)

    // stage the whole chunk: each col = one full 128B line
#pragma unroll
    for (int p = 0; p < 8; ++p) {
        const int col = p * 32 + lc8;
        const int ga  = in0 + col * LSEQ + 4 * lo8;
        sud[col * 17 + lo8]     = pack8(*(const int4*)(u  + ga));
        sud[col * 17 + 8 + lo8] = pack8(*(const int4*)(dt + ga));
    }
#pragma unroll
    for (int j2 = 0; j2 < 2; ++j2) {
        const int n = nB0 + 8 * j2;
        tB[kB * 20 + n] = (float)Bm[(bb * NST + n) * LSEQ + cg * LC + kB];
    }
    __syncthreads();

    float x[NST];
#pragma unroll
    for (int n = 0; n < NST; ++n) x[n] = 0.f;
    float S = 0.f;

    const int* swp = &sud[tid * 17];
#pragma unroll
    for (int k4 = 0; k4 < 8; ++k4) {
        const int uw = swp[k4];                // one ds_read_b32 per stream / 4 steps
        const int dw = swp[8 + k4];
#pragma unroll
        for (int b = 0; b < 4; ++b) {
            const int k = 4 * k4 + b;
            const float uf    = sb(uw, b) * u_s;
            const float delta = softplus_f(sb(dw, b) * dt_s + dtb);
            const float w     = delta * uf * B_s;
            S += delta;
            const float* bt = &tB[k * 20];
            STEP4B(0, bt); STEP4B(1, bt); STEP4B(2, bt); STEP4B(3, bt);
        }
    }

    Sbuf[cg * SCANS + scan] = S;
    float4* Xo = (float4*)(Xbuf + (cg * SCANS + scan) * NST);
#pragma unroll
    for (int q = 0; q < 4; ++q)
        Xo[q] = make_float4(x[4*q], x[4*q+1], x[4*q+2], x[4*q+3]);
}

// ---------------- Combine: fold summaries, write init states in-place ----------------
__global__ __launch_bounds__(256) void qs_combine(
    const int* __restrict__ A_log, const float* __restrict__ A_sp,
    const float* __restrict__ Sbuf, float* __restrict__ Xbuf)
{
    const int idx  = blockIdx.x * 256 + threadIdx.x;   // flat (scan, n)
    const int scan = idx >> 4, n = idx & 15;
    const int d    = scan & (DIM - 1);
    const float A2 = -__builtin_amdgcn_exp2f(
        (float)A_log[d * NST + n] * ((*A_sp) * LOG2E)) * LOG2E;
    float x = 0.f;
#pragma unroll 8
    for (int c = 0; c < K; ++c) {
        const int off = c * (SCANS * NST) + idx;
        const float Xe = Xbuf[off];
        const float P  = __builtin_amdgcn_exp2f(A2 * Sbuf[c * SCANS + scan]);
        Xbuf[off] = x;                                  // init state for chunk c
        x = __builtin_fmaf(P, x, Xe);
    }
}

// ---------------- Phase 2: rerun with true init, emit output ----------------
__global__ __launch_bounds__(256, 4) void qs_phase2(
    const int* __restrict__ u,  const int* __restrict__ dt,
    const int* __restrict__ Bm, const int* __restrict__ Cm,
    const int* __restrict__ z,  const int* __restrict__ A_log,
    const int* __restrict__ Dv, const int* __restrict__ dt_bias,
    const float* __restrict__ u_sp,  const float* __restrict__ dt_sp,
    const float* __restrict__ A_sp,  const float* __restrict__ B_sp,
    const float* __restrict__ C_sp,  const float* __restrict__ z_sp,
    const float* __restrict__ D_sp,  const float* __restrict__ dtb_sp,
    const float* __restrict__ XI, float* __restrict__ out)
{
    const int tid = threadIdx.x;
    const int cg  = blockIdx.x >> 5;
    const int sg  = blockIdx.x & 31;
    const int scan = sg * SPB + tid;
    const int d  = scan & (DIM - 1);
    const int bb = sg >> 4;

    // per col: u 8w | dt 8w | z 8w | pad 1w  (stride 25 words, gcd(25,32)=1)
    __shared__ int   suz[256 * 25];
    __shared__ float tB[LC * 20];
    __shared__ float tC[LC * 20];

    const float u_s = *u_sp, dt_s = *dt_sp, A_s = *A_sp, B_s = *B_sp;
    const float C_s = *C_sp, z_s  = *z_sp,  D_s = *D_sp, dtb_s = *dtb_sp;
    LOAD_A2();
    const float dtb = (float)dt_bias[d] * dtb_s;
    const float Dd  = (float)Dv[d] * D_s;

    float x[NST];
    {
        const float4* xi = (const float4*)(XI + (cg * SCANS + scan) * NST);
        const float4 x0 = xi[0], x1 = xi[1], x2 = xi[2], x3 = xi[3];
        x[0]=x0.x; x[1]=x0.y; x[2]=x0.z; x[3]=x0.w;
        x[4]=x1.x; x[5]=x1.y; x[6]=x1.z; x[7]=x1.w;
        x[8]=x2.x; x[9]=x2.y; x[10]=x2.z; x[11]=x2.w;
        x[12]=x3.x; x[13]=x3.y; x[14]=x3.z; x[15]=x3.w;
    }

    const int lc8 = tid >> 3, lo8 = tid & 7;
    const int in0 = sg * SPB * LSEQ + cg * LC;
    const int kB  = tid & 31, nB0 = tid >> 5;
    const int ob  = scan * LSEQ + cg * LC;     // own output row-chunk base

    // stage the whole chunk: each col = one full 128B line per array
#pragma unroll
    for (int p = 0; p < 8; ++p) {
        const int col = p * 32 + lc8;
        const int ga  = in0 + col * LSEQ + 4 * lo8;
        suz[col * 25 + lo8]      = pack8(*(const int4*)(u  + ga));
        suz[col * 25 + 8 + lo8]  = pack8(*(const int4*)(dt + ga));
        suz[col * 25 + 16 + lo8] = pack8(*(const int4*)(z  + ga));
    }
#pragma unroll
    for (int j2 = 0; j2 < 2; ++j2) {
        const int n  = nB0 + 8 * j2;
        const int gr = (bb * NST + n) * LSEQ + cg * LC + kB;
        tB[kB * 20 + n] = (float)Bm[gr];
        tC[kB * 20 + n] = (float)Cm[gr];
    }
    __syncthreads();

    const int* swp = &suz[tid * 25];
    float ya[16];                              // 64B sector buffer, burst every 16 k
#pragma unroll
    for (int k4 = 0; k4 < 8; ++k4) {
        const int uw = swp[k4];                // one ds_read_b32 per stream / 4 steps
        const int dw = swp[8 + k4];
        const int zw = swp[16 + k4];
#pragma unroll
        for (int b = 0; b < 4; ++b) {
            const int k = 4 * k4 + b;
            const float uf    = sb(uw, b) * u_s;
            const float delta = softplus_f(sb(dw, b) * dt_s + dtb);
            const float w     = delta * uf * B_s;
            const float zf    = sb(zw, b) * z_s;
            const float gate  = zf * __builtin_amdgcn_rcpf(
                                    1.f + __builtin_amdgcn_exp2f(-zf * LOG2E));
            const float* bt = &tB[k * 20];
            const float* ct = &tC[k * 20];
            float y = 0.f;
            STEP4(0, bt, ct); STEP4(1, bt, ct); STEP4(2, bt, ct); STEP4(3, bt, ct);
            ya[k & 15] = __builtin_fmaf(y, C_s, Dd * uf) * gate;
            if ((k & 15) == 15) {              // 4 back-to-back float4 stores:
                float* ob2 = out + ob + (k - 15);   // one fully-dirty 64B sector
#pragma unroll
                for (int q = 0; q < 4; ++q)
                    *(float4*)(ob2 + 4 * q) =
                        make_float4(ya[4*q], ya[4*q+1], ya[4*q+2], ya[4*q+3]);
            }
        }
    }
}

extern "C" void kernel_launch(void* const* d_in, const int* in_sizes, int n_in,
                              void* d_out, int out_size, void* d_ws, size_t ws_size,
                              hipStream_t stream) {
    const int* u   = (const int*)d_in[0];
    const int* dt  = (const int*)d_in[1];
    const int* Bm  = (const int*)d_in[2];
    const int* Cm  = (const int*)d_in[3];
    const int* z   = (const int*)d_in[4];
    const int* Al  = (const int*)d_in[5];
    const int* Dv  = (const int*)d_in[6];
    const int* dtb = (const int*)d_in[7];
    const float* u_sp = (const float*)d_in[8],  * dt_sp = (const float*)d_in[9];
    const float* A_sp = (const float*)d_in[10], * B_sp  = (const float*)d_in[11];
    const float* C_sp = (const float*)d_in[12], * z_sp  = (const float*)d_in[13];
    const float* D_sp = (const float*)d_in[14], * dtb_sp= (const float*)d_in[15];

    float* Xbuf = (float*)d_ws;                          // K*SCANS*NST f32 = 33.6 MiB
    float* Sbuf = Xbuf + (size_t)K * SCANS * NST;        // K*SCANS f32 = 2.1 MiB

    dim3 blk(256);
    qs_phase1<<<dim3(K * NSG), blk, 0, stream>>>(u, dt, Bm, Al, dtb,
        u_sp, dt_sp, A_sp, B_sp, dtb_sp, Sbuf, Xbuf);
    qs_combine<<<dim3(SCANS * NST / 256), blk, 0, stream>>>(Al, A_sp, Sbuf, Xbuf);
    qs_phase2<<<dim3(K * NSG), blk, 0, stream>>>(u, dt, Bm, Cm, z, Al, Dv, dtb,
        u_sp, dt_sp, A_sp, B_sp, C_sp, z_sp, D_sp, dtb_sp, Xbuf, (float*)d_out);
}

// Round 25
// 149.826 us; speedup vs baseline: 6.2027x; 5.2199x over previous
//
#include <hip/hip_runtime.h>

// QSScan: quantized selective scan (Mamba-style), int8-in-int32 + scalar scales.
// Chunked parallel linear recurrence, serial-in-thread, LDS-transpose-staged I/O.
//   phase1: thread=(scan,chunk): local scan from 0 over LC=32 -> X_end[16], S=sum(delta)
//   combine: thread=(scan,n): fold 64 chunks -> true init per chunk
//   phase2: thread=(scan,chunk): rerun from true init -> y=(x.C)*C_s+D*u, silu(z) gate
// R25 = R21 VERBATIM (the verified best: 149.3us, FETCH/WRITE near-ideal, no
// spill). R22 (global-uniform B/C), R23 (register staging), R24 (word reads)
// each regressed 28-520% -- all three tripped the register-allocation cliff
// that R21's byte-read inner loop sits just below. Restoring known-good state:
//   - K=64 chunks (LC=32): each col's chunk = one full 128B line, single stage
//   - combined u|dt|z LDS staging, 100B/col stride (gcd(25,32)=1, conflict-free)
//   - tB/tC LDS broadcast tiles (per-step b128 reads, wave-uniform address)
//   - per-step ds_read_u8 byte consumption (VGPR 48, no spill -- DO NOT restructure)
//   - ya[16] 64B sector-burst stores (R19's write fix)

#define LOG2E 1.44269504088896340736f
#define LN2F  0.69314718055994530942f

constexpr int BATCH = 2;
constexpr int DIM   = 4096;
constexpr int LSEQ  = 2048;
constexpr int NST   = 16;
constexpr int SCANS = BATCH * DIM;   // 8192
constexpr int K     = 64;            // chunks per scan
constexpr int LC    = LSEQ / K;      // 32 timesteps per chunk (= one 128B line)
constexpr int SPB   = 256;           // scans per block (1 chunk per block)
constexpr int NSG   = SCANS / SPB;   // 32 scan-groups

__device__ __forceinline__ float softplus_f(float x) {
    float e = __builtin_amdgcn_exp2f(x * LOG2E);
    return __builtin_amdgcn_logf(1.f + e) * LN2F;
}

__device__ __forceinline__ int pack8(int4 v) {   // values in [-127,127]: exact
    return (v.x & 255) | ((v.y & 255) << 8) | ((v.z & 255) << 16) | ((v.w & 255) << 24);
}

#define LOAD_A2()                                                              \
    float A2[NST];                                                             \
    {                                                                          \
        const int4* ap = (const int4*)(A_log + d * NST);                       \
        int4 a0 = ap[0], a1 = ap[1], a2 = ap[2], a3 = ap[3];                   \
        const int ai[NST] = {a0.x,a0.y,a0.z,a0.w, a1.x,a1.y,a1.z,a1.w,         \
                             a2.x,a2.y,a2.z,a2.w, a3.x,a3.y,a3.z,a3.w};        \
        _Pragma("unroll")                                                      \
        for (int n = 0; n < NST; ++n)                                          \
            A2[n] = -__builtin_amdgcn_exp2f((float)ai[n] * (A_s * LOG2E)) * LOG2E; \
    }

// advance 4 states (q-th quad) and accumulate y; keeps only 2 float4 live
#define STEP4(q, bt, ct)                                                       \
    {                                                                          \
        const float4 Bq = *(const float4*)((bt) + 4 * (q));                    \
        const float4 Cq = *(const float4*)((ct) + 4 * (q));                    \
        x[4*(q)+0] = __builtin_fmaf(__builtin_amdgcn_exp2f(A2[4*(q)+0] * delta), x[4*(q)+0], w * Bq.x); \
        y = __builtin_fmaf(x[4*(q)+0], Cq.x, y);                               \
        x[4*(q)+1] = __builtin_fmaf(__builtin_amdgcn_exp2f(A2[4*(q)+1] * delta), x[4*(q)+1], w * Bq.y); \
        y = __builtin_fmaf(x[4*(q)+1], Cq.y, y);                               \
        x[4*(q)+2] = __builtin_fmaf(__builtin_amdgcn_exp2f(A2[4*(q)+2] * delta), x[4*(q)+2], w * Bq.z); \
        y = __builtin_fmaf(x[4*(q)+2], Cq.z, y);                               \
        x[4*(q)+3] = __builtin_fmaf(__builtin_amdgcn_exp2f(A2[4*(q)+3] * delta), x[4*(q)+3], w * Bq.w); \
        y = __builtin_fmaf(x[4*(q)+3], Cq.w, y);                               \
    }

#define STEP4B(q, bt)                                                          \
    {                                                                          \
        const float4 Bq = *(const float4*)((bt) + 4 * (q));                    \
        x[4*(q)+0] = __builtin_fmaf(__builtin_amdgcn_exp2f(A2[4*(q)+0] * delta), x[4*(q)+0], w * Bq.x); \
        x[4*(q)+1] = __builtin_fmaf(__builtin_amdgcn_exp2f(A2[4*(q)+1] * delta), x[4*(q)+1], w * Bq.y); \
        x[4*(q)+2] = __builtin_fmaf(__builtin_amdgcn_exp2f(A2[4*(q)+2] * delta), x[4*(q)+2], w * Bq.z); \
        x[4*(q)+3] = __builtin_fmaf(__builtin_amdgcn_exp2f(A2[4*(q)+3] * delta), x[4*(q)+3], w * Bq.w); \
    }

// ---------------- Phase 1: per-chunk summaries (X_end, S) ----------------
__global__ __launch_bounds__(256, 4) void qs_phase1(
    const int* __restrict__ u,  const int* __restrict__ dt,
    const int* __restrict__ Bm, const int* __restrict__ A_log,
    const int* __restrict__ dt_bias,
    const float* __restrict__ u_sp, const float* __restrict__ dt_sp,
    const float* __restrict__ A_sp, const float* __restrict__ B_sp,
    const float* __restrict__ dtb_sp,
    float* __restrict__ Sbuf, float* __restrict__ Xbuf)
{
    const int tid = threadIdx.x;
    const int cg  = blockIdx.x >> 5;           // chunk 0..63
    const int sg  = blockIdx.x & 31;           // scan-group 0..31
    const int scan = sg * SPB + tid;
    const int d  = scan & (DIM - 1);
    const int bb = sg >> 4;                    // batch, uniform per block

    // per col: u 8w | dt 8w | pad 1w  (stride 17 words, gcd(17,32)=1)
    __shared__ int   sud[256 * 17];
    __shared__ float tB[LC * 20];

    const float u_s = *u_sp, dt_s = *dt_sp, A_s = *A_sp, B_s = *B_sp, dtb_s = *dtb_sp;
    LOAD_A2();
    const float dtb = (float)dt_bias[d] * dtb_s;

    const int lc8 = tid >> 3, lo8 = tid & 7;   // 8 lanes cover one col's 128B line
    const int in0 = sg * SPB * LSEQ + cg * LC;
    const int kB  = tid & 31, nB0 = tid >> 5;  // B-stage role (32k x 8n x 2)
    const int bcol = tid * 68;                 // own column byte offset

    // stage the whole chunk: each col = one full 128B line
#pragma unroll
    for (int p = 0; p < 8; ++p) {
        const int col = p * 32 + lc8;
        const int ga  = in0 + col * LSEQ + 4 * lo8;
        sud[col * 17 + lo8]     = pack8(*(const int4*)(u  + ga));
        sud[col * 17 + 8 + lo8] = pack8(*(const int4*)(dt + ga));
    }
#pragma unroll
    for (int j2 = 0; j2 < 2; ++j2) {
        const int n = nB0 + 8 * j2;
        tB[kB * 20 + n] = (float)Bm[(bb * NST + n) * LSEQ + cg * LC + kB];
    }
    __syncthreads();

    float x[NST];
#pragma unroll
    for (int n = 0; n < NST; ++n) x[n] = 0.f;
    float S = 0.f;

    const signed char* sc = (const signed char*)sud;
#pragma unroll 4
    for (int k = 0; k < LC; ++k) {
        const float uf    = (float)sc[bcol + k] * u_s;
        const float delta = softplus_f((float)sc[bcol + 32 + k] * dt_s + dtb);
        const float w     = delta * uf * B_s;
        S += delta;
        const float* bt = &tB[k * 20];
        STEP4B(0, bt); STEP4B(1, bt); STEP4B(2, bt); STEP4B(3, bt);
    }

    Sbuf[cg * SCANS + scan] = S;
    float4* Xo = (float4*)(Xbuf + (cg * SCANS + scan) * NST);
#pragma unroll
    for (int q = 0; q < 4; ++q)
        Xo[q] = make_float4(x[4*q], x[4*q+1], x[4*q+2], x[4*q+3]);
}

// ---------------- Combine: fold summaries, write init states in-place ----------------
__global__ __launch_bounds__(256) void qs_combine(
    const int* __restrict__ A_log, const float* __restrict__ A_sp,
    const float* __restrict__ Sbuf, float* __restrict__ Xbuf)
{
    const int idx  = blockIdx.x * 256 + threadIdx.x;   // flat (scan, n)
    const int scan = idx >> 4, n = idx & 15;
    const int d    = scan & (DIM - 1);
    const float A2 = -__builtin_amdgcn_exp2f(
        (float)A_log[d * NST + n] * ((*A_sp) * LOG2E)) * LOG2E;
    float x = 0.f;
#pragma unroll 8
    for (int c = 0; c < K; ++c) {
        const int off = c * (SCANS * NST) + idx;
        const float Xe = Xbuf[off];
        const float P  = __builtin_amdgcn_exp2f(A2 * Sbuf[c * SCANS + scan]);
        Xbuf[off] = x;                                  // init state for chunk c
        x = __builtin_fmaf(P, x, Xe);
    }
}

// ---------------- Phase 2: rerun with true init, emit output ----------------
__global__ __launch_bounds__(256, 4) void qs_phase2(
    const int* __restrict__ u,  const int* __restrict__ dt,
    const int* __restrict__ Bm, const int* __restrict__ Cm,
    const int* __restrict__ z,  const int* __restrict__ A_log,
    const int* __restrict__ Dv, const int* __restrict__ dt_bias,
    const float* __restrict__ u_sp,  const float* __restrict__ dt_sp,
    const float* __restrict__ A_sp,  const float* __restrict__ B_sp,
    const float* __restrict__ C_sp,  const float* __restrict__ z_sp,
    const float* __restrict__ D_sp,  const float* __restrict__ dtb_sp,
    const float* __restrict__ XI, float* __restrict__ out)
{
    const int tid = threadIdx.x;
    const int cg  = blockIdx.x >> 5;
    const int sg  = blockIdx.x & 31;
    const int scan = sg * SPB + tid;
    const int d  = scan & (DIM - 1);
    const int bb = sg >> 4;

    // per col: u 8w | dt 8w | z 8w | pad 1w  (stride 25 words, gcd(25,32)=1)
    __shared__ int   suz[256 * 25];
    __shared__ float tB[LC * 20];
    __shared__ float tC[LC * 20];

    const float u_s = *u_sp, dt_s = *dt_sp, A_s = *A_sp, B_s = *B_sp;
    const float C_s = *C_sp, z_s  = *z_sp,  D_s = *D_sp, dtb_s = *dtb_sp;
    LOAD_A2();
    const float dtb = (float)dt_bias[d] * dtb_s;
    const float Dd  = (float)Dv[d] * D_s;

    float x[NST];
    {
        const float4* xi = (const float4*)(XI + (cg * SCANS + scan) * NST);
        const float4 x0 = xi[0], x1 = xi[1], x2 = xi[2], x3 = xi[3];
        x[0]=x0.x; x[1]=x0.y; x[2]=x0.z; x[3]=x0.w;
        x[4]=x1.x; x[5]=x1.y; x[6]=x1.z; x[7]=x1.w;
        x[8]=x2.x; x[9]=x2.y; x[10]=x2.z; x[11]=x2.w;
        x[12]=x3.x; x[13]=x3.y; x[14]=x3.z; x[15]=x3.w;
    }

    const int lc8 = tid >> 3, lo8 = tid & 7;
    const int in0 = sg * SPB * LSEQ + cg * LC;
    const int kB  = tid & 31, nB0 = tid >> 5;
    const int bcol = tid * 100;
    const int ob   = scan * LSEQ + cg * LC;    // own output row-chunk base

    // stage the whole chunk: each col = one full 128B line per array
#pragma unroll
    for (int p = 0; p < 8; ++p) {
        const int col = p * 32 + lc8;
        const int ga  = in0 + col * LSEQ + 4 * lo8;
        suz[col * 25 + lo8]      = pack8(*(const int4*)(u  + ga));
        suz[col * 25 + 8 + lo8]  = pack8(*(const int4*)(dt + ga));
        suz[col * 25 + 16 + lo8] = pack8(*(const int4*)(z  + ga));
    }
#pragma unroll
    for (int j2 = 0; j2 < 2; ++j2) {
        const int n  = nB0 + 8 * j2;
        const int gr = (bb * NST + n) * LSEQ + cg * LC + kB;
        tB[kB * 20 + n] = (float)Bm[gr];
        tC[kB * 20 + n] = (float)Cm[gr];
    }
    __syncthreads();

    const signed char* sc = (const signed char*)suz;
    float ya[16];                              // 64B sector buffer, burst every 16 k
#pragma unroll 4
    for (int k = 0; k < LC; ++k) {
        const float uf    = (float)sc[bcol + k] * u_s;
        const float delta = softplus_f((float)sc[bcol + 32 + k] * dt_s + dtb);
        const float w     = delta * uf * B_s;
        const float zf    = (float)sc[bcol + 64 + k] * z_s;
        const float gate  = zf * __builtin_amdgcn_rcpf(
                                1.f + __builtin_amdgcn_exp2f(-zf * LOG2E));
        const float* bt = &tB[k * 20];
        const float* ct = &tC[k * 20];
        float y = 0.f;
        STEP4(0, bt, ct); STEP4(1, bt, ct); STEP4(2, bt, ct); STEP4(3, bt, ct);
        ya[k & 15] = __builtin_fmaf(y, C_s, Dd * uf) * gate;
        if ((k & 15) == 15) {                  // 4 back-to-back float4 stores:
            float* ob2 = out + ob + (k - 15);  // one fully-dirty 64B sector
#pragma unroll
            for (int q = 0; q < 4; ++q)
                *(float4*)(ob2 + 4 * q) =
                    make_float4(ya[4*q], ya[4*q+1], ya[4*q+2], ya[4*q+3]);
        }
    }
}

extern "C" void kernel_launch(void* const* d_in, const int* in_sizes, int n_in,
                              void* d_out, int out_size, void* d_ws, size_t ws_size,
                              hipStream_t stream) {
    const int* u   = (const int*)d_in[0];
    const int* dt  = (const int*)d_in[1];
    const int* Bm  = (const int*)d_in[2];
    const int* Cm  = (const int*)d_in[3];
    const int* z   = (const int*)d_in[4];
    const int* Al  = (const int*)d_in[5];
    const int* Dv  = (const int*)d_in[6];
    const int* dtb = (const int*)d_in[7];
    const float* u_sp = (const float*)d_in[8],  * dt_sp = (const float*)d_in[9];
    const float* A_sp = (const float*)d_in[10], * B_sp  = (const float*)d_in[11];
    const float* C_sp = (const float*)d_in[12], * z_sp  = (const float*)d_in[13];
    const float* D_sp = (const float*)d_in[14], * dtb_sp= (const float*)d_in[15];

    float* Xbuf = (float*)d_ws;                          // K*SCANS*NST f32 = 33.6 MiB
    float* Sbuf = Xbuf + (size_t)K * SCANS * NST;        // K*SCANS f32 = 2.1 MiB

    dim3 blk(256);
    qs_phase1<<<dim3(K * NSG), blk, 0, stream>>>(u, dt, Bm, Al, dtb,
        u_sp, dt_sp, A_sp, B_sp, dtb_sp, Sbuf, Xbuf);
    qs_combine<<<dim3(SCANS * NST / 256), blk, 0, stream>>>(Al, A_sp, Sbuf, Xbuf);
    qs_phase2<<<dim3(K * NSG), blk, 0, stream>>>(u, dt, Bm, Cm, z, Al, Dv, dtb,
        u_sp, dt_sp, A_sp, B_sp, C_sp, z_sp, D_sp, dtb_sp, Xbuf, (float*)d_out);
}